// Round 1
// baseline (249.998 us; speedup 1.0000x reference)
//
#include <hip/hip_runtime.h>

#define NUM_JOINTS 24

typedef float fvec4 __attribute__((ext_vector_type(4)));

// Ancestor path (root -> joint) for each joint, padded with -1.
__device__ __constant__ int d_chain[NUM_JOINTS][9] = {
    {0,-1,-1,-1,-1,-1,-1,-1,-1},
    {0,1,-1,-1,-1,-1,-1,-1,-1},
    {0,2,-1,-1,-1,-1,-1,-1,-1},
    {0,3,-1,-1,-1,-1,-1,-1,-1},
    {0,1,4,-1,-1,-1,-1,-1,-1},
    {0,2,5,-1,-1,-1,-1,-1,-1},
    {0,3,6,-1,-1,-1,-1,-1,-1},
    {0,1,4,7,-1,-1,-1,-1,-1},
    {0,2,5,8,-1,-1,-1,-1,-1},
    {0,3,6,9,-1,-1,-1,-1,-1},
    {0,1,4,7,10,-1,-1,-1,-1},
    {0,2,5,8,11,-1,-1,-1,-1},
    {0,3,6,9,12,-1,-1,-1,-1},
    {0,3,6,9,13,-1,-1,-1,-1},
    {0,3,6,9,14,-1,-1,-1,-1},
    {0,3,6,9,12,15,-1,-1,-1},
    {0,3,6,9,13,16,-1,-1,-1},
    {0,3,6,9,14,17,-1,-1,-1},
    {0,3,6,9,13,16,18,-1,-1},
    {0,3,6,9,14,17,19,-1,-1},
    {0,3,6,9,13,16,18,20,-1},
    {0,3,6,9,14,17,19,21,-1},
    {0,3,6,9,13,16,18,20,22},
    {0,3,6,9,14,17,19,21,23},
};

// a*s + c  (vector * scalar + vector)
__device__ __forceinline__ fvec4 fma4s(fvec4 a, float s, fvec4 c) {
    fvec4 r;
    r.x = fmaf(a.x, s, c.x); r.y = fmaf(a.y, s, c.y);
    r.z = fmaf(a.z, s, c.z); r.w = fmaf(a.w, s, c.w);
    return r;
}
// a*b + c  (elementwise)
__device__ __forceinline__ fvec4 fma4v(fvec4 a, fvec4 b, fvec4 c) {
    fvec4 r;
    r.x = fmaf(a.x, b.x, c.x); r.y = fmaf(a.y, b.y, c.y);
    r.z = fmaf(a.z, b.z, c.z); r.w = fmaf(a.w, b.w, c.w);
    return r;
}
// a*s (vector * scalar)
__device__ __forceinline__ fvec4 mul4s(fvec4 a, float s) {
    fvec4 r; r.x = a.x * s; r.y = a.y * s; r.z = a.z * s; r.w = a.w * s;
    return r;
}

// R8 theory: previous ladder (16v/8v/4v-unroll2) all held ~12 KB/SIMD in
// flight -> all ~2.7 TB/s. This version raises BOTH factors of the
// (waves/SIMD) x (outstanding loads/wave) product:
//   - 4 verts/thread -> 6250 waves (~6 waves/SIMD grid-wise, ~5 resident
//     at ~100 VGPR) vs 1.56 for 16v.
//   - explicit depth-8 circular weight prefetch (fully unrolled k-loop,
//     static indices -> stays in VGPRs, rule #20) -> ~8 KB in flight/wave.
// Target: >40 KB/SIMD in flight -> approach the 6.3-6.8 TB/s stream
// ceiling the harness fill kernels demonstrate on this chip.
// No min-waves clause (R6 spill lesson). All loads/stores 64x16B
// unit-stride, non-temporal (192 MB streamed >> 32 MB L2).
#define PF 8

__global__ __launch_bounds__(256) void skin_fused4_kernel(
    const float* __restrict__ normals,
    const float* __restrict__ pose,
    const float* __restrict__ weights,
    float* __restrict__ out,
    int N) {
    __shared__ float L[NUM_JOINTS][9];
    __shared__ fvec4 Rl[NUM_JOINTS][3];  // global rots, rows padded 9->12 floats

    const int b = blockIdx.y;
    const int tid = threadIdx.x;

    // --- chain computation (lanes 0..23 of wave 0) ---
    if (tid < NUM_JOINTS) {
        float x = pose[b * 72 + tid * 3 + 0];
        float y = pose[b * 72 + tid * 3 + 1];
        float z = pose[b * 72 + tid * 3 + 2];
        // reference: angle = norm(axisang + 1e-8); axis = axisang / angle
        float ax = x + 1e-8f, ay = y + 1e-8f, az = z + 1e-8f;
        float angle = sqrtf(ax * ax + ay * ay + az * az);
        float inv = 1.0f / angle;
        float ux = x * inv, uy = y * inv, uz = z * inv;
        float c = __cosf(angle), s = __sinf(angle), t = 1.0f - c;
        L[tid][0] = c + t * ux * ux;
        L[tid][1] = t * ux * uy - s * uz;
        L[tid][2] = t * ux * uz + s * uy;
        L[tid][3] = t * uy * ux + s * uz;
        L[tid][4] = c + t * uy * uy;
        L[tid][5] = t * uy * uz - s * ux;
        L[tid][6] = t * uz * ux - s * uy;
        L[tid][7] = t * uz * uy + s * ux;
        L[tid][8] = c + t * uz * uz;
    }
    __syncthreads();

    if (tid < NUM_JOINTS) {
        // each lane composes its own ancestor path: G = L[c0] @ L[c1] @ ...
        float G[9];
        int j0 = d_chain[tid][0];  // always 0
        #pragma unroll
        for (int e = 0; e < 9; e++) G[e] = L[j0][e];
        #pragma unroll
        for (int d = 1; d < 9; d++) {
            int j = d_chain[tid][d];
            if (j >= 0) {
                float T[9];
                #pragma unroll
                for (int r = 0; r < 3; r++) {
                    #pragma unroll
                    for (int cc = 0; cc < 3; cc++) {
                        T[r * 3 + cc] = G[r * 3 + 0] * L[j][0 * 3 + cc]
                                      + G[r * 3 + 1] * L[j][1 * 3 + cc]
                                      + G[r * 3 + 2] * L[j][2 * 3 + cc];
                    }
                }
                #pragma unroll
                for (int e = 0; e < 9; e++) G[e] = T[e];
            }
        }
        float* Rf = (float*)Rl;
        #pragma unroll
        for (int e = 0; e < 9; e++) Rf[tid * 12 + e] = G[e];
    }
    __syncthreads();

    // --- skinning: one float4 (4 verts) per thread, deep weight prefetch ---
    const int q = blockIdx.x * blockDim.x + tid;  // float4 index within row
    const int nf4 = N >> 2;                       // float4s per row

    const fvec4* __restrict__ Wb = (const fvec4*)(weights + (size_t)b * NUM_JOINTS * N);
    const fvec4* __restrict__ Nb = (const fvec4*)(normals + (size_t)b * 3 * N);
    fvec4* __restrict__ Ob = (fvec4*)(out + (size_t)b * 3 * N);

    if (q < nf4) {
        fvec4 nx = __builtin_nontemporal_load(&Nb[(size_t)0 * nf4 + q]);
        fvec4 ny = __builtin_nontemporal_load(&Nb[(size_t)1 * nf4 + q]);
        fvec4 nz = __builtin_nontemporal_load(&Nb[(size_t)2 * nf4 + q]);

        // prologue: fill the prefetch ring with joints 0..PF-1
        fvec4 w[PF];
        #pragma unroll
        for (int j = 0; j < PF; j++)
            w[j] = __builtin_nontemporal_load(&Wb[(size_t)j * nf4 + q]);

        fvec4 o0 = (fvec4)(0.f), o1 = (fvec4)(0.f), o2 = (fvec4)(0.f);

        #pragma unroll
        for (int k = 0; k < NUM_JOINTS; k++) {
            fvec4 wk = w[k & (PF - 1)];
            if (k + PF < NUM_JOINTS)  // static under full unroll
                w[k & (PF - 1)] =
                    __builtin_nontemporal_load(&Wb[(size_t)(k + PF) * nf4 + q]);
            fvec4 r0 = Rl[k][0];  // {M00,M01,M02,M10}
            fvec4 r1 = Rl[k][1];  // {M11,M12,M20,M21}
            fvec4 r2 = Rl[k][2];  // {M22,pad,pad,pad}
            fvec4 t0 = fma4s(nx, r0.x, fma4s(ny, r0.y, mul4s(nz, r0.z)));
            fvec4 t1 = fma4s(nx, r0.w, fma4s(ny, r1.x, mul4s(nz, r1.y)));
            fvec4 t2 = fma4s(nx, r1.z, fma4s(ny, r1.w, mul4s(nz, r2.x)));
            o0 = fma4v(wk, t0, o0);
            o1 = fma4v(wk, t1, o1);
            o2 = fma4v(wk, t2, o2);
        }

        __builtin_nontemporal_store(o0, &Ob[(size_t)0 * nf4 + q]);
        __builtin_nontemporal_store(o1, &Ob[(size_t)1 * nf4 + q]);
        __builtin_nontemporal_store(o2, &Ob[(size_t)2 * nf4 + q]);
    } else if (q == nf4) {
        // generic tail: vertices [4*nf4, N) (not hit for N=100000: 4|100000)
        const float* Rf = (const float*)Rl;
        for (int n = nf4 * 4; n < N; n++) {
            float vx = normals[(size_t)b * 3 * N + 0 * N + n];
            float vy = normals[(size_t)b * 3 * N + 1 * N + n];
            float vz = normals[(size_t)b * 3 * N + 2 * N + n];
            float s0 = 0.f, s1 = 0.f, s2 = 0.f;
            for (int k = 0; k < NUM_JOINTS; k++) {
                float w = weights[(size_t)b * NUM_JOINTS * N + (size_t)k * N + n];
                float t0 = Rf[k*12+0] * vx + Rf[k*12+1] * vy + Rf[k*12+2] * vz;
                float t1 = Rf[k*12+3] * vx + Rf[k*12+4] * vy + Rf[k*12+5] * vz;
                float t2 = Rf[k*12+6] * vx + Rf[k*12+7] * vy + Rf[k*12+8] * vz;
                s0 = fmaf(w, t0, s0); s1 = fmaf(w, t1, s1); s2 = fmaf(w, t2, s2);
            }
            out[(size_t)b * 3 * N + 0 * N + n] = s0;
            out[(size_t)b * 3 * N + 1 * N + n] = s1;
            out[(size_t)b * 3 * N + 2 * N + n] = s2;
        }
    }
}

extern "C" void kernel_launch(void* const* d_in, const int* in_sizes, int n_in,
                              void* d_out, int out_size, void* d_ws, size_t ws_size,
                              hipStream_t stream) {
    const float* normals = (const float*)d_in[0];  // (B,3,N)
    const float* pose = (const float*)d_in[1];     // (B,72)
    const float* weights = (const float*)d_in[2];  // (B,24,N)
    float* out = (float*)d_out;                    // (B,3,N)

    const int B = in_sizes[1] / 72;
    const int N = in_sizes[0] / (3 * B);

    const int nf4 = N >> 2;
    const int slots = nf4 + 1;                     // +1 thread for generic tail
    const int gx = (slots + 255) / 256;
    skin_fused4_kernel<<<dim3(gx, B), dim3(256), 0, stream>>>(normals, pose, weights, out, N);
}

// Round 2
// 239.791 us; speedup vs baseline: 1.0426x; 1.0426x over previous
//
#include <hip/hip_runtime.h>

#define NUM_JOINTS 24

typedef float fvec4 __attribute__((ext_vector_type(4)));

// Ancestor path (root -> joint) for each joint, padded with -1.
__device__ __constant__ int d_chain[NUM_JOINTS][9] = {
    {0,-1,-1,-1,-1,-1,-1,-1,-1},
    {0,1,-1,-1,-1,-1,-1,-1,-1},
    {0,2,-1,-1,-1,-1,-1,-1,-1},
    {0,3,-1,-1,-1,-1,-1,-1,-1},
    {0,1,4,-1,-1,-1,-1,-1,-1},
    {0,2,5,-1,-1,-1,-1,-1,-1},
    {0,3,6,-1,-1,-1,-1,-1,-1},
    {0,1,4,7,-1,-1,-1,-1,-1},
    {0,2,5,8,-1,-1,-1,-1,-1},
    {0,3,6,9,-1,-1,-1,-1,-1},
    {0,1,4,7,10,-1,-1,-1,-1},
    {0,2,5,8,11,-1,-1,-1,-1},
    {0,3,6,9,12,-1,-1,-1,-1},
    {0,3,6,9,13,-1,-1,-1,-1},
    {0,3,6,9,14,-1,-1,-1,-1},
    {0,3,6,9,12,15,-1,-1,-1},
    {0,3,6,9,13,16,-1,-1,-1},
    {0,3,6,9,14,17,-1,-1,-1},
    {0,3,6,9,13,16,18,-1,-1},
    {0,3,6,9,14,17,19,-1,-1},
    {0,3,6,9,13,16,18,20,-1},
    {0,3,6,9,14,17,19,21,-1},
    {0,3,6,9,13,16,18,20,22},
    {0,3,6,9,14,17,19,21,23},
};

// a*s + c  (vector * scalar + vector)
__device__ __forceinline__ fvec4 fma4s(fvec4 a, float s, fvec4 c) {
    fvec4 r;
    r.x = fmaf(a.x, s, c.x); r.y = fmaf(a.y, s, c.y);
    r.z = fmaf(a.z, s, c.z); r.w = fmaf(a.w, s, c.w);
    return r;
}
// a*b + c  (elementwise)
__device__ __forceinline__ fvec4 fma4v(fvec4 a, fvec4 b, fvec4 c) {
    fvec4 r;
    r.x = fmaf(a.x, b.x, c.x); r.y = fmaf(a.y, b.y, c.y);
    r.z = fmaf(a.z, b.z, c.z); r.w = fmaf(a.w, b.w, c.w);
    return r;
}
// a*s (vector * scalar)
__device__ __forceinline__ fvec4 mul4s(fvec4 a, float s) {
    fvec4 r; r.x = a.x * s; r.y = a.y * s; r.z = a.z * s; r.w = a.w * s;
    return r;
}

// R9: A/B vs round-0 16v (223.9-224.9us): ONLY change is dropping the
// non-temporal hint from the normal/weight LOADS. R8's in-flight-depth
// theory is falsified (4v-PF8 regressed to ~250 despite 3x the in-flight
// bytes/SIMD); the structure-independent ~2.7 TB/s read plateau across
// 16v/8v/4v points at the nt cache-op on reads itself. There is zero
// reuse to protect (each byte read once), so nt-on-loads can only be
// neutral or harmful. Stores keep nt (matches the 6.8 TB/s fill kernels'
// streaming-write behavior).
__global__ __launch_bounds__(256) void skin_fused16_kernel(
    const float* __restrict__ normals,
    const float* __restrict__ pose,
    const float* __restrict__ weights,
    float* __restrict__ out,
    int N) {
    __shared__ float L[NUM_JOINTS][9];
    __shared__ fvec4 Rl[NUM_JOINTS][3];  // global rots, rows padded 9->12 floats

    const int b = blockIdx.y;
    const int tid = threadIdx.x;

    // --- chain computation (lanes 0..23 of wave 0) ---
    if (tid < NUM_JOINTS) {
        float x = pose[b * 72 + tid * 3 + 0];
        float y = pose[b * 72 + tid * 3 + 1];
        float z = pose[b * 72 + tid * 3 + 2];
        // reference: angle = norm(axisang + 1e-8); axis = axisang / angle
        float ax = x + 1e-8f, ay = y + 1e-8f, az = z + 1e-8f;
        float angle = sqrtf(ax * ax + ay * ay + az * az);
        float inv = 1.0f / angle;
        float ux = x * inv, uy = y * inv, uz = z * inv;
        float c = __cosf(angle), s = __sinf(angle), t = 1.0f - c;
        L[tid][0] = c + t * ux * ux;
        L[tid][1] = t * ux * uy - s * uz;
        L[tid][2] = t * ux * uz + s * uy;
        L[tid][3] = t * uy * ux + s * uz;
        L[tid][4] = c + t * uy * uy;
        L[tid][5] = t * uy * uz - s * ux;
        L[tid][6] = t * uz * ux - s * uy;
        L[tid][7] = t * uz * uy + s * ux;
        L[tid][8] = c + t * uz * uz;
    }
    __syncthreads();

    if (tid < NUM_JOINTS) {
        // each lane composes its own ancestor path: G = L[c0] @ L[c1] @ ...
        float G[9];
        int j0 = d_chain[tid][0];  // always 0
        #pragma unroll
        for (int e = 0; e < 9; e++) G[e] = L[j0][e];
        #pragma unroll
        for (int d = 1; d < 9; d++) {
            int j = d_chain[tid][d];
            if (j >= 0) {
                float T[9];
                #pragma unroll
                for (int r = 0; r < 3; r++) {
                    #pragma unroll
                    for (int cc = 0; cc < 3; cc++) {
                        T[r * 3 + cc] = G[r * 3 + 0] * L[j][0 * 3 + cc]
                                      + G[r * 3 + 1] * L[j][1 * 3 + cc]
                                      + G[r * 3 + 2] * L[j][2 * 3 + cc];
                    }
                }
                #pragma unroll
                for (int e = 0; e < 9; e++) G[e] = T[e];
            }
        }
        float* Rf = (float*)Rl;
        #pragma unroll
        for (int e = 0; e < 9; e++) Rf[tid * 12 + e] = G[e];
    }
    __syncthreads();

    // --- skinning ---
    const int q = blockIdx.x * blockDim.x + tid;  // stream-0 float4 index
    const int nf4 = N >> 2;                       // float4s per row
    const int n16 = nf4 >> 2;                     // float4s per stream (4 streams)

    const fvec4* __restrict__ Wb = (const fvec4*)(weights + (size_t)b * NUM_JOINTS * N);
    const fvec4* __restrict__ Nb = (const fvec4*)(normals + (size_t)b * 3 * N);
    fvec4* __restrict__ Ob = (fvec4*)(out + (size_t)b * 3 * N);

    if (q < n16) {
        int qg[4];
        #pragma unroll
        for (int g = 0; g < 4; g++) qg[g] = q + g * n16;

        fvec4 nx[4], ny[4], nz[4], o0[4], o1[4], o2[4];
        #pragma unroll
        for (int g = 0; g < 4; g++) {
            nx[g] = Nb[(size_t)0 * nf4 + qg[g]];
            ny[g] = Nb[(size_t)1 * nf4 + qg[g]];
            nz[g] = Nb[(size_t)2 * nf4 + qg[g]];
            o0[g] = (fvec4)(0.f); o1[g] = (fvec4)(0.f); o2[g] = (fvec4)(0.f);
        }

        #pragma unroll 2
        for (int k = 0; k < NUM_JOINTS; k++) {
            fvec4 w[4];
            #pragma unroll
            for (int g = 0; g < 4; g++)
                w[g] = Wb[(size_t)k * nf4 + qg[g]];
            fvec4 r0 = Rl[k][0];  // {M00,M01,M02,M10}
            fvec4 r1 = Rl[k][1];  // {M11,M12,M20,M21}
            fvec4 r2 = Rl[k][2];  // {M22,pad,pad,pad}
            #pragma unroll
            for (int g = 0; g < 4; g++) {
                fvec4 t0 = fma4s(nx[g], r0.x, fma4s(ny[g], r0.y, mul4s(nz[g], r0.z)));
                fvec4 t1 = fma4s(nx[g], r0.w, fma4s(ny[g], r1.x, mul4s(nz[g], r1.y)));
                fvec4 t2 = fma4s(nx[g], r1.z, fma4s(ny[g], r1.w, mul4s(nz[g], r2.x)));
                o0[g] = fma4v(w[g], t0, o0[g]);
                o1[g] = fma4v(w[g], t1, o1[g]);
                o2[g] = fma4v(w[g], t2, o2[g]);
            }
        }

        #pragma unroll
        for (int g = 0; g < 4; g++) {
            __builtin_nontemporal_store(o0[g], &Ob[(size_t)0 * nf4 + qg[g]]);
            __builtin_nontemporal_store(o1[g], &Ob[(size_t)1 * nf4 + qg[g]]);
            __builtin_nontemporal_store(o2[g], &Ob[(size_t)2 * nf4 + qg[g]]);
        }
    } else if (q == n16) {
        // generic tail: vertices [16*n16, N) (not hit for N=100000: 100000=16*6250)
        const float* Rf = (const float*)Rl;
        for (int n = n16 * 16; n < N; n++) {
            float vx = normals[(size_t)b * 3 * N + 0 * N + n];
            float vy = normals[(size_t)b * 3 * N + 1 * N + n];
            float vz = normals[(size_t)b * 3 * N + 2 * N + n];
            float s0 = 0.f, s1 = 0.f, s2 = 0.f;
            for (int k = 0; k < NUM_JOINTS; k++) {
                float w = weights[(size_t)b * NUM_JOINTS * N + (size_t)k * N + n];
                float t0 = Rf[k*12+0] * vx + Rf[k*12+1] * vy + Rf[k*12+2] * vz;
                float t1 = Rf[k*12+3] * vx + Rf[k*12+4] * vy + Rf[k*12+5] * vz;
                float t2 = Rf[k*12+6] * vx + Rf[k*12+7] * vy + Rf[k*12+8] * vz;
                s0 = fmaf(w, t0, s0); s1 = fmaf(w, t1, s1); s2 = fmaf(w, t2, s2);
            }
            out[(size_t)b * 3 * N + 0 * N + n] = s0;
            out[(size_t)b * 3 * N + 1 * N + n] = s1;
            out[(size_t)b * 3 * N + 2 * N + n] = s2;
        }
    }
}

extern "C" void kernel_launch(void* const* d_in, const int* in_sizes, int n_in,
                              void* d_out, int out_size, void* d_ws, size_t ws_size,
                              hipStream_t stream) {
    const float* normals = (const float*)d_in[0];  // (B,3,N)
    const float* pose = (const float*)d_in[1];     // (B,72)
    const float* weights = (const float*)d_in[2];  // (B,24,N)
    float* out = (float*)d_out;                    // (B,3,N)

    const int B = in_sizes[1] / 72;
    const int N = in_sizes[0] / (3 * B);

    const int n16 = (N >> 2) >> 2;                 // float4s per stream
    const int slots = n16 + 1;                     // +1 thread for generic tail
    const int gx = (slots + 255) / 256;
    skin_fused16_kernel<<<dim3(gx, B), dim3(256), 0, stream>>>(normals, pose, weights, out, N);
}

// Round 3
// 233.279 us; speedup vs baseline: 1.0717x; 1.0279x over previous
//
#include <hip/hip_runtime.h>

#define NUM_JOINTS 24

typedef float fvec4 __attribute__((ext_vector_type(4)));

// Ancestor path (root -> joint) for each joint, padded with -1.
__device__ __constant__ int d_chain[NUM_JOINTS][9] = {
    {0,-1,-1,-1,-1,-1,-1,-1,-1},
    {0,1,-1,-1,-1,-1,-1,-1,-1},
    {0,2,-1,-1,-1,-1,-1,-1,-1},
    {0,3,-1,-1,-1,-1,-1,-1,-1},
    {0,1,4,-1,-1,-1,-1,-1,-1},
    {0,2,5,-1,-1,-1,-1,-1,-1},
    {0,3,6,-1,-1,-1,-1,-1,-1},
    {0,1,4,7,-1,-1,-1,-1,-1},
    {0,2,5,8,-1,-1,-1,-1,-1},
    {0,3,6,9,-1,-1,-1,-1,-1},
    {0,1,4,7,10,-1,-1,-1,-1},
    {0,2,5,8,11,-1,-1,-1,-1},
    {0,3,6,9,12,-1,-1,-1,-1},
    {0,3,6,9,13,-1,-1,-1,-1},
    {0,3,6,9,14,-1,-1,-1,-1},
    {0,3,6,9,12,15,-1,-1,-1},
    {0,3,6,9,13,16,-1,-1,-1},
    {0,3,6,9,14,17,-1,-1,-1},
    {0,3,6,9,13,16,18,-1,-1},
    {0,3,6,9,14,17,19,-1,-1},
    {0,3,6,9,13,16,18,20,-1},
    {0,3,6,9,14,17,19,21,-1},
    {0,3,6,9,13,16,18,20,22},
    {0,3,6,9,14,17,19,21,23},
};

// a*s + c  (vector * scalar + vector)
__device__ __forceinline__ fvec4 fma4s(fvec4 a, float s, fvec4 c) {
    fvec4 r;
    r.x = fmaf(a.x, s, c.x); r.y = fmaf(a.y, s, c.y);
    r.z = fmaf(a.z, s, c.z); r.w = fmaf(a.w, s, c.w);
    return r;
}
// a*b + c  (elementwise)
__device__ __forceinline__ fvec4 fma4v(fvec4 a, fvec4 b, fvec4 c) {
    fvec4 r;
    r.x = fmaf(a.x, b.x, c.x); r.y = fmaf(a.y, b.y, c.y);
    r.z = fmaf(a.z, b.z, c.z); r.w = fmaf(a.w, b.w, c.w);
    return r;
}
// a*s (vector * scalar)
__device__ __forceinline__ fvec4 mul4s(fvec4 a, float s) {
    fvec4 r; r.x = a.x * s; r.y = a.y * s; r.z = a.z * s; r.w = a.w * s;
    return r;
}

// R10 theory: round-0's 71us kernel runs 400 blocks on 256 CUs -> 144 CUs
// carry 2 blocks, 112 carry 1; runtime set by the 2-block CUs. Their per-CU
// read rate (864KB/71us = 12.2 GB/s/CU) EQUALS the m13 float4-copy read
// ceiling (3.15 TB/s read /256 CU = 12.3 GB/s/CU) -> per-CU rate is already
// at the streaming ceiling; the loss is pure grid imbalance (~0.78 CU-util).
// Fix: gx=32 -> 512 blocks = exactly 2/CU, each block owns a contiguous
// ~196-chunk slice (threads tid>=cnt idle; q stays wave-contiguous so all
// loads remain 64x16B). Inner loop is byte-identical to round-0 (nt loads
// KEPT: R9 showed removing them costs +15us -- dirty-poison eviction storm).
// Predicted: kernel 71 -> ~55us, dur 225 -> ~208.
__global__ __launch_bounds__(256) void skin_fused16_kernel(
    const float* __restrict__ normals,
    const float* __restrict__ pose,
    const float* __restrict__ weights,
    float* __restrict__ out,
    int N) {
    __shared__ float L[NUM_JOINTS][9];
    __shared__ fvec4 Rl[NUM_JOINTS][3];  // global rots, rows padded 9->12 floats

    const int b = blockIdx.y;
    const int tid = threadIdx.x;

    // --- chain computation (lanes 0..23 of wave 0) ---
    if (tid < NUM_JOINTS) {
        float x = pose[b * 72 + tid * 3 + 0];
        float y = pose[b * 72 + tid * 3 + 1];
        float z = pose[b * 72 + tid * 3 + 2];
        // reference: angle = norm(axisang + 1e-8); axis = axisang / angle
        float ax = x + 1e-8f, ay = y + 1e-8f, az = z + 1e-8f;
        float angle = sqrtf(ax * ax + ay * ay + az * az);
        float inv = 1.0f / angle;
        float ux = x * inv, uy = y * inv, uz = z * inv;
        float c = __cosf(angle), s = __sinf(angle), t = 1.0f - c;
        L[tid][0] = c + t * ux * ux;
        L[tid][1] = t * ux * uy - s * uz;
        L[tid][2] = t * ux * uz + s * uy;
        L[tid][3] = t * uy * ux + s * uz;
        L[tid][4] = c + t * uy * uy;
        L[tid][5] = t * uy * uz - s * ux;
        L[tid][6] = t * uz * ux - s * uy;
        L[tid][7] = t * uz * uy + s * ux;
        L[tid][8] = c + t * uz * uz;
    }
    __syncthreads();

    if (tid < NUM_JOINTS) {
        // each lane composes its own ancestor path: G = L[c0] @ L[c1] @ ...
        float G[9];
        int j0 = d_chain[tid][0];  // always 0
        #pragma unroll
        for (int e = 0; e < 9; e++) G[e] = L[j0][e];
        #pragma unroll
        for (int d = 1; d < 9; d++) {
            int j = d_chain[tid][d];
            if (j >= 0) {
                float T[9];
                #pragma unroll
                for (int r = 0; r < 3; r++) {
                    #pragma unroll
                    for (int cc = 0; cc < 3; cc++) {
                        T[r * 3 + cc] = G[r * 3 + 0] * L[j][0 * 3 + cc]
                                      + G[r * 3 + 1] * L[j][1 * 3 + cc]
                                      + G[r * 3 + 2] * L[j][2 * 3 + cc];
                    }
                }
                #pragma unroll
                for (int e = 0; e < 9; e++) G[e] = T[e];
            }
        }
        float* Rf = (float*)Rl;
        #pragma unroll
        for (int e = 0; e < 9; e++) Rf[tid * 12 + e] = G[e];
    }
    __syncthreads();

    // --- skinning ---
    const int nf4 = N >> 2;                       // float4s per row
    const int n16 = nf4 >> 2;                     // float4s per stream (= chunks/batch)

    // balanced slice mapping: block bx owns chunks [bx*per_block, bx*per_block+cnt)
    const int per_block = (n16 + gridDim.x - 1) / gridDim.x;
    const int base = blockIdx.x * per_block;
    int cnt = n16 - base;
    if (cnt > per_block) cnt = per_block;
    if (cnt < 0) cnt = 0;

    const fvec4* __restrict__ Wb = (const fvec4*)(weights + (size_t)b * NUM_JOINTS * N);
    const fvec4* __restrict__ Nb = (const fvec4*)(normals + (size_t)b * 3 * N);
    fvec4* __restrict__ Ob = (fvec4*)(out + (size_t)b * 3 * N);

    // stride loop degenerates to <=1 iteration for this shape (cnt<=196<256)
    for (int q = base + tid; q < base + cnt; q += blockDim.x) {
        int qg[4];
        #pragma unroll
        for (int g = 0; g < 4; g++) qg[g] = q + g * n16;

        fvec4 nx[4], ny[4], nz[4], o0[4], o1[4], o2[4];
        #pragma unroll
        for (int g = 0; g < 4; g++) {
            nx[g] = __builtin_nontemporal_load(&Nb[(size_t)0 * nf4 + qg[g]]);
            ny[g] = __builtin_nontemporal_load(&Nb[(size_t)1 * nf4 + qg[g]]);
            nz[g] = __builtin_nontemporal_load(&Nb[(size_t)2 * nf4 + qg[g]]);
            o0[g] = (fvec4)(0.f); o1[g] = (fvec4)(0.f); o2[g] = (fvec4)(0.f);
        }

        #pragma unroll 2
        for (int k = 0; k < NUM_JOINTS; k++) {
            fvec4 w[4];
            #pragma unroll
            for (int g = 0; g < 4; g++)
                w[g] = __builtin_nontemporal_load(&Wb[(size_t)k * nf4 + qg[g]]);
            fvec4 r0 = Rl[k][0];  // {M00,M01,M02,M10}
            fvec4 r1 = Rl[k][1];  // {M11,M12,M20,M21}
            fvec4 r2 = Rl[k][2];  // {M22,pad,pad,pad}
            #pragma unroll
            for (int g = 0; g < 4; g++) {
                fvec4 t0 = fma4s(nx[g], r0.x, fma4s(ny[g], r0.y, mul4s(nz[g], r0.z)));
                fvec4 t1 = fma4s(nx[g], r0.w, fma4s(ny[g], r1.x, mul4s(nz[g], r1.y)));
                fvec4 t2 = fma4s(nx[g], r1.z, fma4s(ny[g], r1.w, mul4s(nz[g], r2.x)));
                o0[g] = fma4v(w[g], t0, o0[g]);
                o1[g] = fma4v(w[g], t1, o1[g]);
                o2[g] = fma4v(w[g], t2, o2[g]);
            }
        }

        #pragma unroll
        for (int g = 0; g < 4; g++) {
            __builtin_nontemporal_store(o0[g], &Ob[(size_t)0 * nf4 + qg[g]]);
            __builtin_nontemporal_store(o1[g], &Ob[(size_t)1 * nf4 + qg[g]]);
            __builtin_nontemporal_store(o2[g], &Ob[(size_t)2 * nf4 + qg[g]]);
        }
    }

    // generic tail: vertices [16*n16, N) (empty for N=100000 = 16*6250)
    if (blockIdx.x == 0 && tid == 0) {
        const float* Rf = (const float*)Rl;
        for (int n = n16 * 16; n < N; n++) {
            float vx = normals[(size_t)b * 3 * N + 0 * N + n];
            float vy = normals[(size_t)b * 3 * N + 1 * N + n];
            float vz = normals[(size_t)b * 3 * N + 2 * N + n];
            float s0 = 0.f, s1 = 0.f, s2 = 0.f;
            for (int k = 0; k < NUM_JOINTS; k++) {
                float w = weights[(size_t)b * NUM_JOINTS * N + (size_t)k * N + n];
                float t0 = Rf[k*12+0] * vx + Rf[k*12+1] * vy + Rf[k*12+2] * vz;
                float t1 = Rf[k*12+3] * vx + Rf[k*12+4] * vy + Rf[k*12+5] * vz;
                float t2 = Rf[k*12+6] * vx + Rf[k*12+7] * vy + Rf[k*12+8] * vz;
                s0 = fmaf(w, t0, s0); s1 = fmaf(w, t1, s1); s2 = fmaf(w, t2, s2);
            }
            out[(size_t)b * 3 * N + 0 * N + n] = s0;
            out[(size_t)b * 3 * N + 1 * N + n] = s1;
            out[(size_t)b * 3 * N + 2 * N + n] = s2;
        }
    }
}

extern "C" void kernel_launch(void* const* d_in, const int* in_sizes, int n_in,
                              void* d_out, int out_size, void* d_ws, size_t ws_size,
                              hipStream_t stream) {
    const float* normals = (const float*)d_in[0];  // (B,3,N)
    const float* pose = (const float*)d_in[1];     // (B,72)
    const float* weights = (const float*)d_in[2];  // (B,24,N)
    float* out = (float*)d_out;                    // (B,3,N)

    const int B = in_sizes[1] / 72;
    const int N = in_sizes[0] / (3 * B);

    // 512 blocks total (2 per CU on 256 CUs), balanced contiguous slices.
    int gx = 512 / B;
    if (gx < 1) gx = 1;
    skin_fused16_kernel<<<dim3(gx, B), dim3(256), 0, stream>>>(normals, pose, weights, out, N);
}

// Round 4
// 222.721 us; speedup vs baseline: 1.1225x; 1.0474x over previous
//
#include <hip/hip_runtime.h>

#define NUM_JOINTS 24

typedef float fvec4 __attribute__((ext_vector_type(4)));

// Ancestor path (root -> joint) for each joint, padded with -1.
__device__ __constant__ int d_chain[NUM_JOINTS][9] = {
    {0,-1,-1,-1,-1,-1,-1,-1,-1},
    {0,1,-1,-1,-1,-1,-1,-1,-1},
    {0,2,-1,-1,-1,-1,-1,-1,-1},
    {0,3,-1,-1,-1,-1,-1,-1,-1},
    {0,1,4,-1,-1,-1,-1,-1,-1},
    {0,2,5,-1,-1,-1,-1,-1,-1},
    {0,3,6,-1,-1,-1,-1,-1,-1},
    {0,1,4,7,-1,-1,-1,-1,-1},
    {0,2,5,8,-1,-1,-1,-1,-1},
    {0,3,6,9,-1,-1,-1,-1,-1},
    {0,1,4,7,10,-1,-1,-1,-1},
    {0,2,5,8,11,-1,-1,-1,-1},
    {0,3,6,9,12,-1,-1,-1,-1},
    {0,3,6,9,13,-1,-1,-1,-1},
    {0,3,6,9,14,-1,-1,-1,-1},
    {0,3,6,9,12,15,-1,-1,-1},
    {0,3,6,9,13,16,-1,-1,-1},
    {0,3,6,9,14,17,-1,-1,-1},
    {0,3,6,9,13,16,18,-1,-1},
    {0,3,6,9,14,17,19,-1,-1},
    {0,3,6,9,13,16,18,20,-1},
    {0,3,6,9,14,17,19,21,-1},
    {0,3,6,9,13,16,18,20,22},
    {0,3,6,9,14,17,19,21,23},
};

// a*s + c  (vector * scalar + vector)
__device__ __forceinline__ fvec4 fma4s(fvec4 a, float s, fvec4 c) {
    fvec4 r;
    r.x = fmaf(a.x, s, c.x); r.y = fmaf(a.y, s, c.y);
    r.z = fmaf(a.z, s, c.z); r.w = fmaf(a.w, s, c.w);
    return r;
}
// a*b + c  (elementwise)
__device__ __forceinline__ fvec4 fma4v(fvec4 a, fvec4 b, fvec4 c) {
    fvec4 r;
    r.x = fmaf(a.x, b.x, c.x); r.y = fmaf(a.y, b.y, c.y);
    r.z = fmaf(a.z, b.z, c.z); r.w = fmaf(a.w, b.w, c.w);
    return r;
}
// a*s (vector * scalar)
__device__ __forceinline__ fvec4 mul4s(fvec4 a, float s) {
    fvec4 r; r.x = a.x * s; r.y = a.y * s; r.z = a.z * s; r.w = a.w * s;
    return r;
}

// R11 theory: per-CU total stream rate is pinned at ~55-60% of the m13
// copy-kernel rate across ALL geometry variants (R8 depth: -25us, R9
// cache-op: -15us, R10 balance: compensated null). The untouched
// structural difference vs a copy kernel is DRAM page locality: baseline
// reads 27 isolated 1KB chunks per wave-visit (groups 100KB apart,
// k-planes 400KB apart). Fix: wave-blocked group mapping
//   c(q,g) = (q>>6)*256 + g*64 + (q&63)
// -> per wave, the 4 group loads of each k-plane cover 4KB CONTIGUOUS
// (16KB per block) instead of 4x1KB at 100KB spacing. Everything else
// (nt loads+stores, unroll-2, 400-block geometry, register structure)
// byte-identical to the 224.9 baseline. Ragged edge (nf4 % 256 != 0):
// clamp load addresses, predicate stores.
__global__ __launch_bounds__(256) void skin_fused16_kernel(
    const float* __restrict__ normals,
    const float* __restrict__ pose,
    const float* __restrict__ weights,
    float* __restrict__ out,
    int N) {
    __shared__ float L[NUM_JOINTS][9];
    __shared__ fvec4 Rl[NUM_JOINTS][3];  // global rots, rows padded 9->12 floats

    const int b = blockIdx.y;
    const int tid = threadIdx.x;

    // --- chain computation (lanes 0..23 of wave 0) ---
    if (tid < NUM_JOINTS) {
        float x = pose[b * 72 + tid * 3 + 0];
        float y = pose[b * 72 + tid * 3 + 1];
        float z = pose[b * 72 + tid * 3 + 2];
        // reference: angle = norm(axisang + 1e-8); axis = axisang / angle
        float ax = x + 1e-8f, ay = y + 1e-8f, az = z + 1e-8f;
        float angle = sqrtf(ax * ax + ay * ay + az * az);
        float inv = 1.0f / angle;
        float ux = x * inv, uy = y * inv, uz = z * inv;
        float c = __cosf(angle), s = __sinf(angle), t = 1.0f - c;
        L[tid][0] = c + t * ux * ux;
        L[tid][1] = t * ux * uy - s * uz;
        L[tid][2] = t * ux * uz + s * uy;
        L[tid][3] = t * uy * ux + s * uz;
        L[tid][4] = c + t * uy * uy;
        L[tid][5] = t * uy * uz - s * ux;
        L[tid][6] = t * uz * ux - s * uy;
        L[tid][7] = t * uz * uy + s * ux;
        L[tid][8] = c + t * uz * uz;
    }
    __syncthreads();

    if (tid < NUM_JOINTS) {
        // each lane composes its own ancestor path: G = L[c0] @ L[c1] @ ...
        float G[9];
        int j0 = d_chain[tid][0];  // always 0
        #pragma unroll
        for (int e = 0; e < 9; e++) G[e] = L[j0][e];
        #pragma unroll
        for (int d = 1; d < 9; d++) {
            int j = d_chain[tid][d];
            if (j >= 0) {
                float T[9];
                #pragma unroll
                for (int r = 0; r < 3; r++) {
                    #pragma unroll
                    for (int cc = 0; cc < 3; cc++) {
                        T[r * 3 + cc] = G[r * 3 + 0] * L[j][0 * 3 + cc]
                                      + G[r * 3 + 1] * L[j][1 * 3 + cc]
                                      + G[r * 3 + 2] * L[j][2 * 3 + cc];
                    }
                }
                #pragma unroll
                for (int e = 0; e < 9; e++) G[e] = T[e];
            }
        }
        float* Rf = (float*)Rl;
        #pragma unroll
        for (int e = 0; e < 9; e++) Rf[tid * 12 + e] = G[e];
    }
    __syncthreads();

    // --- skinning ---
    const int q = blockIdx.x * blockDim.x + tid;
    const int nf4 = N >> 2;                       // float4s per row

    const fvec4* __restrict__ Wb = (const fvec4*)(weights + (size_t)b * NUM_JOINTS * N);
    const fvec4* __restrict__ Nb = (const fvec4*)(normals + (size_t)b * 3 * N);
    fvec4* __restrict__ Ob = (fvec4*)(out + (size_t)b * 3 * N);

    if (nf4 > 0) {
        // wave-blocked group mapping: wave-group wg covers chunks
        // [wg*256, wg*256+256); lane l takes g*64 + l within it.
        const int wg = q >> 6;
        const int lane = q & 63;
        int cg[4];
        bool ok[4];
        bool any = false;
        #pragma unroll
        for (int g = 0; g < 4; g++) {
            int c = wg * 256 + g * 64 + lane;
            ok[g] = (c < nf4);
            any = any || ok[g];
            cg[g] = ok[g] ? c : (nf4 - 1);  // clamp: safe load, store masked
        }

        if (any) {
            fvec4 nx[4], ny[4], nz[4], o0[4], o1[4], o2[4];
            #pragma unroll
            for (int g = 0; g < 4; g++) {
                nx[g] = __builtin_nontemporal_load(&Nb[(size_t)0 * nf4 + cg[g]]);
                ny[g] = __builtin_nontemporal_load(&Nb[(size_t)1 * nf4 + cg[g]]);
                nz[g] = __builtin_nontemporal_load(&Nb[(size_t)2 * nf4 + cg[g]]);
                o0[g] = (fvec4)(0.f); o1[g] = (fvec4)(0.f); o2[g] = (fvec4)(0.f);
            }

            #pragma unroll 2
            for (int k = 0; k < NUM_JOINTS; k++) {
                fvec4 w[4];
                #pragma unroll
                for (int g = 0; g < 4; g++)
                    w[g] = __builtin_nontemporal_load(&Wb[(size_t)k * nf4 + cg[g]]);
                fvec4 r0 = Rl[k][0];  // {M00,M01,M02,M10}
                fvec4 r1 = Rl[k][1];  // {M11,M12,M20,M21}
                fvec4 r2 = Rl[k][2];  // {M22,pad,pad,pad}
                #pragma unroll
                for (int g = 0; g < 4; g++) {
                    fvec4 t0 = fma4s(nx[g], r0.x, fma4s(ny[g], r0.y, mul4s(nz[g], r0.z)));
                    fvec4 t1 = fma4s(nx[g], r0.w, fma4s(ny[g], r1.x, mul4s(nz[g], r1.y)));
                    fvec4 t2 = fma4s(nx[g], r1.z, fma4s(ny[g], r1.w, mul4s(nz[g], r2.x)));
                    o0[g] = fma4v(w[g], t0, o0[g]);
                    o1[g] = fma4v(w[g], t1, o1[g]);
                    o2[g] = fma4v(w[g], t2, o2[g]);
                }
            }

            #pragma unroll
            for (int g = 0; g < 4; g++) {
                if (ok[g]) {
                    __builtin_nontemporal_store(o0[g], &Ob[(size_t)0 * nf4 + cg[g]]);
                    __builtin_nontemporal_store(o1[g], &Ob[(size_t)1 * nf4 + cg[g]]);
                    __builtin_nontemporal_store(o2[g], &Ob[(size_t)2 * nf4 + cg[g]]);
                }
            }
        }
    }

    // generic tail: vertices [4*nf4, N) (empty for N=100000: 4 | 100000)
    if (blockIdx.x == 0 && tid == 0) {
        const float* Rf = (const float*)Rl;
        for (int n = nf4 * 4; n < N; n++) {
            float vx = normals[(size_t)b * 3 * N + 0 * N + n];
            float vy = normals[(size_t)b * 3 * N + 1 * N + n];
            float vz = normals[(size_t)b * 3 * N + 2 * N + n];
            float s0 = 0.f, s1 = 0.f, s2 = 0.f;
            for (int k = 0; k < NUM_JOINTS; k++) {
                float w = weights[(size_t)b * NUM_JOINTS * N + (size_t)k * N + n];
                float t0 = Rf[k*12+0] * vx + Rf[k*12+1] * vy + Rf[k*12+2] * vz;
                float t1 = Rf[k*12+3] * vx + Rf[k*12+4] * vy + Rf[k*12+5] * vz;
                float t2 = Rf[k*12+6] * vx + Rf[k*12+7] * vy + Rf[k*12+8] * vz;
                s0 = fmaf(w, t0, s0); s1 = fmaf(w, t1, s1); s2 = fmaf(w, t2, s2);
            }
            out[(size_t)b * 3 * N + 0 * N + n] = s0;
            out[(size_t)b * 3 * N + 1 * N + n] = s1;
            out[(size_t)b * 3 * N + 2 * N + n] = s2;
        }
    }
}

extern "C" void kernel_launch(void* const* d_in, const int* in_sizes, int n_in,
                              void* d_out, int out_size, void* d_ws, size_t ws_size,
                              hipStream_t stream) {
    const float* normals = (const float*)d_in[0];  // (B,3,N)
    const float* pose = (const float*)d_in[1];     // (B,72)
    const float* weights = (const float*)d_in[2];  // (B,24,N)
    float* out = (float*)d_out;                    // (B,3,N)

    const int B = in_sizes[1] / 72;
    const int N = in_sizes[0] / (3 * B);

    // one thread per 16 verts, wave-blocked: wave-group wg covers 256
    // consecutive chunks; q spans ngroups*64 threads. (round-0 geometry:
    // 25 blocks/batch x 16 batches = 400 blocks for N=100000)
    const int nf4 = N >> 2;
    const int ngroups = (nf4 + 255) / 256;
    const int qspan = ngroups * 64;
    const int gx = (qspan + 255) / 256 > 0 ? (qspan + 255) / 256 : 1;
    skin_fused16_kernel<<<dim3(gx, B), dim3(256), 0, stream>>>(normals, pose, weights, out, N);
}